// Round 1
// 103.276 us; speedup vs baseline: 1.0396x; 1.0396x over previous
//
#include <hip/hip_runtime.h>
#include <hip/hip_bf16.h>
#include <math.h>

#define N_NODES 8192
#define DIM 256
#define WPR 256      // bitmap words per row = 8192/32
#define LSTRIDE 128  // adjacency list stride (ushort); max degree ~60 << 128

typedef __attribute__((ext_vector_type(8))) short bf16x8;
typedef __attribute__((ext_vector_type(4))) float f32x4;

// ---------------- kernel 1: zero bitmap + convert x,W to bf16 ----------------
// grid 2048 x 256 = 524288 threads; each zeroes one uint4 of the 8 MB bitmap,
// first 270336 threads also convert 8 fp32 -> 8 bf16 (x then W).
__global__ __launch_bounds__(256) void init_all(const float* __restrict__ x,
                                                const float* __restrict__ W,
                                                unsigned* __restrict__ bitmap,
                                                __hip_bfloat16* __restrict__ xb,
                                                __hip_bfloat16* __restrict__ Wb) {
    unsigned tid = blockIdx.x * 256 + threadIdx.x;
    uint4 z = {0u, 0u, 0u, 0u};
    ((uint4*)bitmap)[tid] = z;
    const unsigned NX8 = N_NODES * DIM / 8;  // 262144
    if (tid < NX8 + DIM * DIM / 8) {
        const float* src = x;
        __hip_bfloat16* dst = xb;
        size_t off = (size_t)tid * 8;
        if (tid >= NX8) { src = W; dst = Wb; off = (size_t)(tid - NX8) * 8; }
        float4 v0 = *(const float4*)(src + off);
        float4 v1 = *(const float4*)(src + off + 4);
        union { __hip_bfloat16 h[8]; uint4 u; } t;
        t.h[0] = __float2bfloat16(v0.x); t.h[1] = __float2bfloat16(v0.y);
        t.h[2] = __float2bfloat16(v0.z); t.h[3] = __float2bfloat16(v0.w);
        t.h[4] = __float2bfloat16(v1.x); t.h[5] = __float2bfloat16(v1.y);
        t.h[6] = __float2bfloat16(v1.z); t.h[7] = __float2bfloat16(v1.w);
        *(uint4*)(dst + off) = t.u;
    }
}

// ---------------- kernel 2: scatter edges into dedup bitmap ----------------
__global__ __launch_bounds__(256) void scatter_edges(const int* __restrict__ rows,
                                                     const int* __restrict__ cols,
                                                     unsigned* __restrict__ bitmap, int E) {
    int e = blockIdx.x * 256 + threadIdx.x;
    if (e >= E) return;
    int r = rows[e];
    int c = cols[e];
    atomicOr(&bitmap[(size_t)r * WPR + (c >> 5)], 1u << (c & 31));
}

// ---------------- kernel 3: popcount -> d_inv AND emit compact neighbor list ----------------
// one wave per row: lane holds uint4 (128 bits); wave prefix-sum places set bits.
__global__ __launch_bounds__(256) void dinv_and_list(const unsigned* __restrict__ bitmap,
                                                     float* __restrict__ dinv,
                                                     int* __restrict__ lens,
                                                     unsigned short* __restrict__ list) {
    int wave = threadIdx.x >> 6;
    int lane = threadIdx.x & 63;
    int row = blockIdx.x * 4 + wave;
    const uint4* base = (const uint4*)(bitmap + (size_t)row * WPR);
    uint4 w = base[lane];
    int c = __popc(w.x) + __popc(w.y) + __popc(w.z) + __popc(w.w);
    // diagonal presence
    int dw = row >> 5;
    int diag = 0;
    if ((dw >> 2) == lane) {
        unsigned word = ((dw & 3) == 0) ? w.x : ((dw & 3) == 1) ? w.y : ((dw & 3) == 2) ? w.z : w.w;
        diag = (int)((word >> (row & 31)) & 1u);
    }
    unsigned long long db = __ballot(diag);
    // inclusive prefix sum of per-lane popcounts
    int p = c;
#pragma unroll
    for (int off = 1; off < 64; off <<= 1) {
        int v = __shfl_up(p, off);
        if (lane >= off) p += v;
    }
    int total = __shfl(p, 63);
    // scatter this lane's set-bit column ids at its exclusive-prefix position
    unsigned short* lp = list + (size_t)row * LSTRIDE + (p - c);
    int k = 0;
    unsigned ws[4] = {w.x, w.y, w.z, w.w};
#pragma unroll
    for (int q = 0; q < 4; q++) {
        unsigned ww = ws[q];
        int bc = lane * 128 + q * 32;
        while (ww) {
            int b = __builtin_ctz(ww);
            ww &= ww - 1;
            lp[k++] = (unsigned short)(bc + b);
        }
    }
    int len = total + (db == 0ull ? 1 : 0);
    if (db == 0ull && lane == 0) list[(size_t)row * LSTRIDE + total] = (unsigned short)row;
    if (lane == 0) {
        lens[row] = len;
        dinv[row] = 1.0f / sqrtf((float)len + 1e-5f);
    }
}

// ---------------- kernel 4: g = bf16( dinv .* (x @ W^T) ) via MFMA ----------------
// grid (128, 4); block 256 = 4 waves; wave computes 16(m) x 64(n)  [unchanged, verified]
__global__ __launch_bounds__(256) void gemm_mfma(const short* __restrict__ xb,
                                                 const short* __restrict__ Wb,
                                                 const float* __restrict__ dinv,
                                                 __hip_bfloat16* __restrict__ g) {
    int wave = threadIdx.x >> 6;
    int lane = threadIdx.x & 63;
    int bm = blockIdx.x * 64 + wave * 16;
    int bn = blockIdx.y * 64;
    int quad = lane >> 4;
    int l16 = lane & 15;
    f32x4 acc[4] = {};
    const short* arow = xb + (size_t)(bm + l16) * DIM + quad * 8;
#pragma unroll
    for (int k0 = 0; k0 < DIM; k0 += 32) {
        bf16x8 a = *(const bf16x8*)(arow + k0);
#pragma unroll
        for (int s = 0; s < 4; s++) {
            bf16x8 b = *(const bf16x8*)(Wb + (size_t)(bn + s * 16 + l16) * DIM + k0 + quad * 8);
            acc[s] = __builtin_amdgcn_mfma_f32_16x16x32_bf16(a, b, acc[s], 0, 0, 0);
        }
    }
    // C/D layout: col = lane&15 (n), row = quad*4 + r (m)
#pragma unroll
    for (int r = 0; r < 4; r++) {
        int m = bm + quad * 4 + r;
        float s0 = dinv[m];
#pragma unroll
        for (int s = 0; s < 4; s++)
            g[(size_t)m * DIM + bn + s * 16 + l16] = __float2bfloat16(s0 * acc[s][r]);
    }
}

// ---------------- kernel 5: out[i] = relu(dinv[i] * sum_{j in list(i)} g[j]) ----------------
// 128 threads/row: 4 neighbor-groups x 32 lanes; each lane gathers 16 B (8 bf16 feats)
// per neighbor; cross-group reduce in LDS at the end.
__global__ __launch_bounds__(128) void aggregate(const unsigned short* __restrict__ list,
                                                 const int* __restrict__ lens,
                                                 const uint4* __restrict__ g4,   // g rows as 32x uint4
                                                 const float* __restrict__ dinv,
                                                 float* __restrict__ out) {
    __shared__ unsigned short snbr[LSTRIDE];
    __shared__ float part[4][DIM];
    int row = blockIdx.x;
    int tid = threadIdx.x;
    snbr[tid] = list[(size_t)row * LSTRIDE + tid];
    int len = lens[row];
    __syncthreads();
    int gq = tid >> 5, l = tid & 31;
    float a0 = 0.f, a1 = 0.f, a2 = 0.f, a3 = 0.f, a4 = 0.f, a5 = 0.f, a6 = 0.f, a7 = 0.f;
    float b0 = 0.f, b1 = 0.f, b2 = 0.f, b3 = 0.f, b4 = 0.f, b5 = 0.f, b6 = 0.f, b7 = 0.f;
    int i = gq;
    for (; i + 4 < len; i += 8) {
        int n0 = snbr[i];
        int n1 = snbr[i + 4];
        uint4 u0 = g4[(size_t)n0 * 32 + l];
        uint4 u1 = g4[(size_t)n1 * 32 + l];
        a0 += __uint_as_float(u0.x << 16); a1 += __uint_as_float(u0.x & 0xffff0000u);
        a2 += __uint_as_float(u0.y << 16); a3 += __uint_as_float(u0.y & 0xffff0000u);
        a4 += __uint_as_float(u0.z << 16); a5 += __uint_as_float(u0.z & 0xffff0000u);
        a6 += __uint_as_float(u0.w << 16); a7 += __uint_as_float(u0.w & 0xffff0000u);
        b0 += __uint_as_float(u1.x << 16); b1 += __uint_as_float(u1.x & 0xffff0000u);
        b2 += __uint_as_float(u1.y << 16); b3 += __uint_as_float(u1.y & 0xffff0000u);
        b4 += __uint_as_float(u1.z << 16); b5 += __uint_as_float(u1.z & 0xffff0000u);
        b6 += __uint_as_float(u1.w << 16); b7 += __uint_as_float(u1.w & 0xffff0000u);
    }
    if (i < len) {
        int n0 = snbr[i];
        uint4 u0 = g4[(size_t)n0 * 32 + l];
        a0 += __uint_as_float(u0.x << 16); a1 += __uint_as_float(u0.x & 0xffff0000u);
        a2 += __uint_as_float(u0.y << 16); a3 += __uint_as_float(u0.y & 0xffff0000u);
        a4 += __uint_as_float(u0.z << 16); a5 += __uint_as_float(u0.z & 0xffff0000u);
        a6 += __uint_as_float(u0.w << 16); a7 += __uint_as_float(u0.w & 0xffff0000u);
    }
    float* pp = &part[gq][l * 8];
    pp[0] = a0 + b0; pp[1] = a1 + b1; pp[2] = a2 + b2; pp[3] = a3 + b3;
    pp[4] = a4 + b4; pp[5] = a5 + b5; pp[6] = a6 + b6; pp[7] = a7 + b7;
    __syncthreads();
    int f0 = tid * 2;
    float s = dinv[row];
    float r0 = (part[0][f0] + part[1][f0]) + (part[2][f0] + part[3][f0]);
    float r1 = (part[0][f0 + 1] + part[1][f0 + 1]) + (part[2][f0 + 1] + part[3][f0 + 1]);
    float2 o;
    o.x = fmaxf(s * r0, 0.f);
    o.y = fmaxf(s * r1, 0.f);
    *(float2*)(out + (size_t)row * DIM + f0) = o;
}

extern "C" void kernel_launch(void* const* d_in, const int* in_sizes, int n_in,
                              void* d_out, int out_size, void* d_ws, size_t ws_size,
                              hipStream_t stream) {
    const float* x = (const float*)d_in[0];
    const int* ei = (const int*)d_in[1];   // [2, E] flat: rows then cols
    const float* W = (const float*)d_in[2];
    float* out = (float*)d_out;
    int E = in_sizes[1] / 2;

    unsigned char* ws = (unsigned char*)d_ws;
    size_t off = 0;
    unsigned* bitmap = (unsigned*)(ws + off); off += (size_t)N_NODES * WPR * 4;          // 8 MB
    float* dinv = (float*)(ws + off);         off += (size_t)N_NODES * 4;                // 32 KB
    int* lens = (int*)(ws + off);             off += (size_t)N_NODES * 4;                // 32 KB
    unsigned short* list = (unsigned short*)(ws + off); off += (size_t)N_NODES * LSTRIDE * 2; // 2 MB
    __hip_bfloat16* xb = (__hip_bfloat16*)(ws + off); off += (size_t)N_NODES * DIM * 2;  // 4 MB
    __hip_bfloat16* Wb = (__hip_bfloat16*)(ws + off); off += (size_t)DIM * DIM * 2;      // 128 KB
    __hip_bfloat16* g = (__hip_bfloat16*)(ws + off);  off += (size_t)N_NODES * DIM * 2;  // 4 MB

    init_all<<<2048, 256, 0, stream>>>(x, W, bitmap, xb, Wb);
    scatter_edges<<<(E + 255) / 256, 256, 0, stream>>>(ei, ei + E, bitmap, E);
    dinv_and_list<<<N_NODES / 4, 256, 0, stream>>>(bitmap, dinv, lens, list);
    dim3 ggrid(N_NODES / 64, DIM / 64);
    gemm_mfma<<<ggrid, 256, 0, stream>>>((const short*)xb, (const short*)Wb, dinv, g);
    aggregate<<<N_NODES, 128, 0, stream>>>(list, lens, (const uint4*)g, dinv, out);
}